// Round 13
// baseline (3906.868 us; speedup 1.0000x reference)
//
#include <hip/hip_runtime.h>
#include <hip/hip_bf16.h>
#include <stdint.h>

// B,S,H,I = 4,2048,4096,11008 ; M = B*S = 8192
static constexpr int Hd = 4096;
static constexpr int Id = 11008;
static constexpr int Md = 8192;

using short8 = __attribute__((ext_vector_type(8))) short;
using f32x4  = __attribute__((ext_vector_type(4))) float;

__device__ __forceinline__ unsigned short f2bf(float x) {
    union { float f; unsigned u; } v; v.f = x;
    unsigned r = v.u + 0x7FFF + ((v.u >> 16) & 1);   // RNE
    return (unsigned short)(r >> 16);
}

typedef const __attribute__((address_space(1))) unsigned int* as1_u32p;
typedef __attribute__((address_space(3))) unsigned int* as3_u32p;

__device__ __forceinline__ void gload16(const unsigned short* g, unsigned short* l) {
    __builtin_amdgcn_global_load_lds((as1_u32p)(const void*)g, (as3_u32p)(void*)l, 16, 0, 0);
}

// swizzled chunk offset (ushort index) within a [rows][64 cols] bf16 tile.
#define AOFF(r, c) ((((r) * 8) + ((c) ^ ((r) & 7))) * 8)

// counted lgkm wait usable before MFMA: needs sched_barrier (rule #18)
#define LGKMW(n) do { asm volatile("s_waitcnt lgkmcnt(" #n ")" ::: "memory"); \
                      __builtin_amdgcn_sched_barrier(0); } while (0)
// pre-barrier partial drain (no sched fence needed; barrier follows)
#define LGKMP(n) do { asm volatile("s_waitcnt lgkmcnt(" #n ")" ::: "memory"); } while (0)
#define VMCNT(n) do { asm volatile("s_waitcnt vmcnt(" #n ")" ::: "memory"); \
                      __builtin_amdgcn_sched_barrier(0); } while (0)
#define BARRIER() do { asm volatile("" ::: "memory"); __builtin_amdgcn_s_barrier(); \
                       asm volatile("" ::: "memory"); } while (0)

// ---------------------------------------------------------------------------
// fp32 -> bf16 bulk converter: all 4 tensors in one launch
// ---------------------------------------------------------------------------
__global__ __launch_bounds__(256) void k_cvt4(
    const float* __restrict__ s0, unsigned short* __restrict__ d0, int n0,
    const float* __restrict__ s1, unsigned short* __restrict__ d1, int n1,
    const float* __restrict__ s2, unsigned short* __restrict__ d2, int n2,
    const float* __restrict__ s3, unsigned short* __restrict__ d3, int n3)
{
    const int total = n0 + n1 + n2 + n3;
    int i = blockIdx.x * blockDim.x + threadIdx.x;
    const int stride = gridDim.x * blockDim.x;
    for (; i < total; i += stride) {
        const float* s; unsigned short* d; int j = i;
        if (j < n0) { s = s0; d = d0; }
        else { j -= n0;
            if (j < n1) { s = s1; d = d1; }
            else { j -= n1;
                if (j < n2) { s = s2; d = d2; }
                else { j -= n2; s = s3; d = d3; }
            }
        }
        f32x4 a = *(const f32x4*)(s + (size_t)j * 8);
        f32x4 b = *(const f32x4*)(s + (size_t)j * 8 + 4);
        short8 v;
        v[0] = (short)f2bf(a[0]); v[1] = (short)f2bf(a[1]);
        v[2] = (short)f2bf(a[2]); v[3] = (short)f2bf(a[3]);
        v[4] = (short)f2bf(b[0]); v[5] = (short)f2bf(b[1]);
        v[6] = (short)f2bf(b[2]); v[7] = (short)f2bf(b[3]);
        *reinterpret_cast<short8*>(d + (size_t)j * 8) = v;
    }
}

// ===========================================================================
// FUSED up+gate kernel. Structure = proven R9/R12; ds_reads software-
// pipelined one phase ahead (within-tile only). Stage placement, vmcnt
// ledger, and barrier count UNCHANGED.
// Read issue: P1 = {af-lo(8), gf(4), uf(4,RA)}; P2 = {af2-hi(8,RA)}.
// Waits: P1 pre-BAR lgkm(8), post-BAR lgkm(4) [af-lo+gf done, uf flying];
//        P2 post-BAR lgkm(8) [uf done, af2 flying]; P3 lgkm(0) [af2 done].
// Race audit: uf lands <= P2-wait; Us staged @P3-top after P2-end BAR. ✓
//             af2 lands <= P3-wait; As staged @P4-top after P3-end BAR. ✓
//             gf lands <= P1-wait; Gs staged @P2-top after P1-end BAR. ✓
// ===========================================================================
template<int D>
__device__ __forceinline__ void ug_body(
    unsigned short (&As)[2][2][8192], unsigned short (&Gs)[2][8192], unsigned short (&Us)[2][8192],
    const unsigned short* pA0, const unsigned short* pA1,
    const unsigned short* pG0, const unsigned short* pG1,
    const unsigned short* pU0, const unsigned short* pU1,
    int stoff, bool pf,
    int wm, int wn, int r16, int kg, int wave,
    f32x4 (&accg)[8][2], f32x4 (&accu)[8][2])
{
    constexpr size_t hK = (size_t)128 * Hd;
    short8 af[4][2], af2[4][2], gf[2][2], uf[2][2];

    // ---- P1: reads af-lo + gf (this phase) + uf (read-ahead for P2) ----
    #pragma unroll
    for (int mi = 0; mi < 4; ++mi)
        #pragma unroll
        for (int kk = 0; kk < 2; ++kk)
            af[mi][kk] = *(const short8*)&As[D][wm][AOFF(mi * 16 + r16, kk * 4 + kg)];
    #pragma unroll
    for (int ni = 0; ni < 2; ++ni)
        #pragma unroll
        for (int kk = 0; kk < 2; ++kk)
            gf[ni][kk] = *(const short8*)&Gs[D][AOFF(wn * 32 + ni * 16 + r16, kk * 4 + kg)];
    #pragma unroll
    for (int ni = 0; ni < 2; ++ni)
        #pragma unroll
        for (int kk = 0; kk < 2; ++kk)
            uf[ni][kk] = *(const short8*)&Us[D][AOFF(wn * 32 + ni * 16 + r16, kk * 4 + kg)];
    LGKMP(8);
    BARRIER();
    LGKMW(4);            // af-lo + gf landed; uf still in flight under MFMA1
    __builtin_amdgcn_s_setprio(1);
    #pragma unroll
    for (int mi = 0; mi < 4; ++mi)
        #pragma unroll
        for (int ni = 0; ni < 2; ++ni)
            #pragma unroll
            for (int kk = 0; kk < 2; ++kk)
                accg[mi][ni] = __builtin_amdgcn_mfma_f32_16x16x32_bf16(af[mi][kk], gf[ni][kk], accg[mi][ni], 0, 0, 0);
    __builtin_amdgcn_s_setprio(0);
    BARRIER();

    // ---- P2: stage G(t+2); read-ahead af2-hi (for P3); MFMA U mi0-3 ----
    if (pf) {
        gload16(pG0 + stoff, &Gs[D][wave * 512]);
        gload16(pG1 + stoff, &Gs[D][4096 + wave * 512]);
    }
    #pragma unroll
    for (int mi = 0; mi < 4; ++mi)
        #pragma unroll
        for (int kk = 0; kk < 2; ++kk)
            af2[mi][kk] = *(const short8*)&As[D][wm][AOFF((mi + 4) * 16 + r16, kk * 4 + kg)];
    BARRIER();
    LGKMW(8);            // uf landed; af2 still in flight under MFMA2
    __builtin_amdgcn_s_setprio(1);
    #pragma unroll
    for (int mi = 0; mi < 4; ++mi)
        #pragma unroll
        for (int ni = 0; ni < 2; ++ni)
            #pragma unroll
            for (int kk = 0; kk < 2; ++kk)
                accu[mi][ni] = __builtin_amdgcn_mfma_f32_16x16x32_bf16(af[mi][kk], uf[ni][kk], accu[mi][ni], 0, 0, 0);
    __builtin_amdgcn_s_setprio(0);
    BARRIER();

    // ---- P3: stage U(t+2); MFMA G mi4-7 (af2 + resident gf) ----
    if (pf) {
        gload16(pU0 + stoff, &Us[D][wave * 512]);
        gload16(pU1 + stoff, &Us[D][4096 + wave * 512]);
    }
    BARRIER();
    LGKMW(0);            // af2 landed
    __builtin_amdgcn_s_setprio(1);
    #pragma unroll
    for (int mi = 0; mi < 4; ++mi)
        #pragma unroll
        for (int ni = 0; ni < 2; ++ni)
            #pragma unroll
            for (int kk = 0; kk < 2; ++kk)
                accg[mi + 4][ni] = __builtin_amdgcn_mfma_f32_16x16x32_bf16(af2[mi][kk], gf[ni][kk], accg[mi + 4][ni], 0, 0, 0);
    __builtin_amdgcn_s_setprio(0);
    BARRIER();

    // ---- P4: stage A(t+2); MFMA U mi4-7 (regs resident) ----
    if (pf) {
        gload16(pA0 + stoff,      &As[D][0][wave * 512]);
        gload16(pA1 + stoff,      &As[D][0][4096 + wave * 512]);
        gload16(pA0 + hK + stoff, &As[D][1][wave * 512]);
        gload16(pA1 + hK + stoff, &As[D][1][4096 + wave * 512]);
    }
    __builtin_amdgcn_s_setprio(1);
    #pragma unroll
    for (int mi = 0; mi < 4; ++mi)
        #pragma unroll
        for (int ni = 0; ni < 2; ++ni)
            #pragma unroll
            for (int kk = 0; kk < 2; ++kk)
                accu[mi + 4][ni] = __builtin_amdgcn_mfma_f32_16x16x32_bf16(af2[mi][kk], uf[ni][kk], accu[mi + 4][ni], 0, 0, 0);
    __builtin_amdgcn_s_setprio(0);
    if (pf) { VMCNT(8); }
    else    { VMCNT(0); }
    BARRIER();
}

__global__ __launch_bounds__(512, 2) void k_upgate(
    const unsigned short* __restrict__ A,
    const unsigned short* __restrict__ G,
    const unsigned short* __restrict__ U,
    unsigned short* __restrict__ inter)
{
    __shared__ unsigned short As[2][2][8192];
    __shared__ unsigned short Gs[2][8192];
    __shared__ unsigned short Us[2][8192];

    const int tid  = threadIdx.x;
    const int wave = tid >> 6;
    const int lane = tid & 63;
    const int wm   = wave >> 2;
    const int wn   = wave & 3;
    const int r16  = lane & 15;
    const int kg   = lane >> 4;

    const int nwg = gridDim.x;           // 2752
    const int bid = blockIdx.x;
    const int swz = (bid & 7) * (nwg >> 3) + (bid >> 3);
    const int grp = swz / 688;
    const int rem = swz % 688;
    const int m0  = (grp * 8 + (rem & 7)) * 256;
    const int n0  = (rem >> 3) * 128;

    const int i0 = tid,       r0 = i0 >> 3;
    const int i1 = 512 + tid, r1 = i1 >> 3;
    const int cc0 = (i0 & 7) ^ (r0 & 7);
    const int cc1 = (i1 & 7) ^ (r1 & 7);
    constexpr size_t hK = (size_t)128 * Hd;

    const unsigned short* pA0 = A + (size_t)(m0 + r0) * Hd + cc0 * 8;
    const unsigned short* pA1 = A + (size_t)(m0 + r1) * Hd + cc1 * 8;
    const unsigned short* pG0 = G + (size_t)(n0 + r0) * Hd + cc0 * 8;
    const unsigned short* pG1 = G + (size_t)(n0 + r1) * Hd + cc1 * 8;
    const unsigned short* pU0 = U + (size_t)(n0 + r0) * Hd + cc0 * 8;
    const unsigned short* pU1 = U + (size_t)(n0 + r1) * Hd + cc1 * 8;

    f32x4 accg[8][2] = {};
    f32x4 accu[8][2] = {};

    constexpr int NT = Hd >> 6;   // 64

    // prologue: tile 0 (A,G,U) + tile 1 (A,G,U) = 16 loads
    gload16(pA0,      &As[0][0][wave * 512]);
    gload16(pA1,      &As[0][0][4096 + wave * 512]);
    gload16(pA0 + hK, &As[0][1][wave * 512]);
    gload16(pA1 + hK, &As[0][1][4096 + wave * 512]);
    gload16(pG0,      &Gs[0][wave * 512]);
    gload16(pG1,      &Gs[0][4096 + wave * 512]);
    gload16(pU0,      &Us[0][wave * 512]);
    gload16(pU1,      &Us[0][4096 + wave * 512]);
    gload16(pA0 + 64,      &As[1][0][wave * 512]);
    gload16(pA1 + 64,      &As[1][0][4096 + wave * 512]);
    gload16(pA0 + hK + 64, &As[1][1][wave * 512]);
    gload16(pA1 + hK + 64, &As[1][1][4096 + wave * 512]);
    gload16(pG0 + 64, &Gs[1][wave * 512]);
    gload16(pG1 + 64, &Gs[1][4096 + wave * 512]);
    gload16(pU0 + 64, &Us[1][wave * 512]);
    gload16(pU1 + 64, &Us[1][4096 + wave * 512]);
    VMCNT(8);      // tile 0 landed; tile 1 in flight
    BARRIER();

    for (int kt = 0; kt < NT; kt += 2) {
        const bool pf0 = (kt + 2) < NT;
        const bool pf1 = (kt + 3) < NT;
        ug_body<0>(As, Gs, Us, pA0, pA1, pG0, pG1, pU0, pU1,
                   128, pf0, wm, wn, r16, kg, wave, accg, accu);
        ug_body<1>(As, Gs, Us, pA0, pA1, pG0, pG1, pU0, pU1,
                   192, pf1, wm, wn, r16, kg, wave, accg, accu);
        pA0 += 128; pA1 += 128; pG0 += 128; pG1 += 128; pU0 += 128; pU1 += 128;
    }

    #pragma unroll
    for (int mi = 0; mi < 8; ++mi)
        #pragma unroll
        for (int ni = 0; ni < 2; ++ni) {
            const int row = m0 + wm * 128 + mi * 16 + kg * 4;
            const int col = n0 + wn * 32 + ni * 16 + r16;
            f32x4 g = accg[mi][ni], u = accu[mi][ni];
            #pragma unroll
            for (int rr = 0; rr < 4; ++rr) {
                float gv = g[rr];
                float s  = gv / (1.0f + __expf(-gv));
                inter[(size_t)(row + rr) * Id + col] = f2bf(s * u[rr]);
            }
        }
}

// ===========================================================================
// Down GEMM. Same pipelined-read transformation on the proven R12 skeleton.
// Read issue: P1 = {af-lo(8), b0f(4), b1f(4,RA)}; P2 = {af2-hi(8,RA)}.
// Waits: P1 pre-BAR lgkm(8), post-BAR lgkm(4); P2 lgkm(8); P3 lgkm(0).
// Race audit: b1f lands <= P2-wait; Bs staged @P3-top after P2-end BAR. ✓
//             af2 lands <= P3-wait; As staged @P4-top after P3-end BAR. ✓
// ===========================================================================
template<int D>
__device__ __forceinline__ void ktile_body(
    unsigned short (&As)[2][2][8192], unsigned short (&Bs)[2][2][8192],
    const unsigned short* pA0, const unsigned short* pA1,
    const unsigned short* pB0, const unsigned short* pB1,
    size_t hK, int stoff, bool pf,
    int wm, int wn, int r16, int kg, int wave,
    f32x4 (&acc)[8][4])
{
    short8 af[4][2], af2[4][2], b0f[2][2], b1f[2][2];

    // ---- P1: reads af-lo + b0f (this phase) + b1f (read-ahead) ----
    #pragma unroll
    for (int mi = 0; mi < 4; ++mi)
        #pragma unroll
        for (int kk = 0; kk < 2; ++kk)
            af[mi][kk] = *(const short8*)&As[D][wm][AOFF(mi * 16 + r16, kk * 4 + kg)];
    #pragma unroll
    for (int ni = 0; ni < 2; ++ni)
        #pragma unroll
        for (int kk = 0; kk < 2; ++kk)
            b0f[ni][kk] = *(const short8*)&Bs[D][wn >> 1][AOFF((wn & 1) * 64 + ni * 16 + r16, kk * 4 + kg)];
    #pragma unroll
    for (int ni = 0; ni < 2; ++ni)
        #pragma unroll
        for (int kk = 0; kk < 2; ++kk)
            b1f[ni][kk] = *(const short8*)&Bs[D][wn >> 1][AOFF((wn & 1) * 64 + (ni + 2) * 16 + r16, kk * 4 + kg)];
    LGKMP(8);
    BARRIER();
    LGKMW(4);            // af-lo + b0f landed; b1f in flight under MFMA1
    __builtin_amdgcn_s_setprio(1);
    #pragma unroll
    for (int mi = 0; mi < 4; ++mi)
        #pragma unroll
        for (int ni = 0; ni < 2; ++ni)
            #pragma unroll
            for (int kk = 0; kk < 2; ++kk)
                acc[mi][ni] = __builtin_amdgcn_mfma_f32_16x16x32_bf16(af[mi][kk], b0f[ni][kk], acc[mi][ni], 0, 0, 0);
    __builtin_amdgcn_s_setprio(0);
    BARRIER();

    // ---- P2: read-ahead af2-hi; MFMA b1f quadrant ----
    #pragma unroll
    for (int mi = 0; mi < 4; ++mi)
        #pragma unroll
        for (int kk = 0; kk < 2; ++kk)
            af2[mi][kk] = *(const short8*)&As[D][wm][AOFF((mi + 4) * 16 + r16, kk * 4 + kg)];
    BARRIER();
    LGKMW(8);            // b1f landed; af2 in flight under MFMA2
    __builtin_amdgcn_s_setprio(1);
    #pragma unroll
    for (int mi = 0; mi < 4; ++mi)
        #pragma unroll
        for (int ni = 0; ni < 2; ++ni)
            #pragma unroll
            for (int kk = 0; kk < 2; ++kk)
                acc[mi][ni + 2] = __builtin_amdgcn_mfma_f32_16x16x32_bf16(af[mi][kk], b1f[ni][kk], acc[mi][ni + 2], 0, 0, 0);
    __builtin_amdgcn_s_setprio(0);
    BARRIER();

    // ---- P3: stage B(t+2); MFMA af2 x b1f ----
    if (pf) {
        gload16(pB0 + stoff,      &Bs[D][0][wave * 512]);
        gload16(pB1 + stoff,      &Bs[D][0][4096 + wave * 512]);
        gload16(pB0 + hK + stoff, &Bs[D][1][wave * 512]);
        gload16(pB1 + hK + stoff, &Bs[D][1][4096 + wave * 512]);
    }
    BARRIER();
    LGKMW(0);            // af2 landed
    __builtin_amdgcn_s_setprio(1);
    #pragma unroll
    for (int mi = 0; mi < 4; ++mi)
        #pragma unroll
        for (int ni = 0; ni < 2; ++ni)
            #pragma unroll
            for (int kk = 0; kk < 2; ++kk)
                acc[mi + 4][ni + 2] = __builtin_amdgcn_mfma_f32_16x16x32_bf16(af2[mi][kk], b1f[ni][kk], acc[mi + 4][ni + 2], 0, 0, 0);
    __builtin_amdgcn_s_setprio(0);
    BARRIER();

    // ---- P4: stage A(t+2); MFMA af2 x b0f (regs resident) ----
    if (pf) {
        gload16(pA0 + stoff,      &As[D][0][wave * 512]);
        gload16(pA1 + stoff,      &As[D][0][4096 + wave * 512]);
        gload16(pA0 + hK + stoff, &As[D][1][wave * 512]);
        gload16(pA1 + hK + stoff, &As[D][1][4096 + wave * 512]);
    }
    __builtin_amdgcn_s_setprio(1);
    #pragma unroll
    for (int mi = 0; mi < 4; ++mi)
        #pragma unroll
        for (int ni = 0; ni < 2; ++ni)
            #pragma unroll
            for (int kk = 0; kk < 2; ++kk)
                acc[mi + 4][ni] = __builtin_amdgcn_mfma_f32_16x16x32_bf16(af2[mi][kk], b0f[ni][kk], acc[mi + 4][ni], 0, 0, 0);
    __builtin_amdgcn_s_setprio(0);
    if (pf) { VMCNT(8); }
    else    { VMCNT(0); }
    BARRIER();
}

__global__ __launch_bounds__(512, 2) void k_down(
    const unsigned short* __restrict__ A, const unsigned short* __restrict__ B,
    float* __restrict__ Cf, const int K, const int ldC)
{
    __shared__ unsigned short As[2][2][8192];
    __shared__ unsigned short Bs[2][2][8192];

    const int tid  = threadIdx.x;
    const int wave = tid >> 6;
    const int lane = tid & 63;
    const int wm   = wave >> 2;
    const int wn   = wave & 3;
    const int r16  = lane & 15;
    const int kg   = lane >> 4;

    const int nwg = gridDim.x;           // 512
    const int bid = blockIdx.x;
    const int swz = (bid & 7) * (nwg >> 3) + (bid >> 3);
    const int grp = swz / 128;
    const int rem = swz % 128;
    const int m0  = (grp * 8 + (rem & 7)) * 256;
    const int n0  = (rem >> 3) * 256;

    const int i0 = tid,       r0 = i0 >> 3;
    const int i1 = 512 + tid, r1 = i1 >> 3;
    const int cc0 = (i0 & 7) ^ (r0 & 7);
    const int cc1 = (i1 & 7) ^ (r1 & 7);
    const size_t hK = (size_t)128 * K;

    const unsigned short* pA0 = A + (size_t)(m0 + r0) * K + cc0 * 8;
    const unsigned short* pA1 = A + (size_t)(m0 + r1) * K + cc1 * 8;
    const unsigned short* pB0 = B + (size_t)(n0 + r0) * K + cc0 * 8;
    const unsigned short* pB1 = B + (size_t)(n0 + r1) * K + cc1 * 8;

    f32x4 acc[8][4] = {};

    const int NT = K >> 6;   // 172

    gload16(pA0,      &As[0][0][wave * 512]);
    gload16(pA1,      &As[0][0][4096 + wave * 512]);
    gload16(pA0 + hK, &As[0][1][wave * 512]);
    gload16(pA1 + hK, &As[0][1][4096 + wave * 512]);
    gload16(pB0,      &Bs[0][0][wave * 512]);
    gload16(pB1,      &Bs[0][0][4096 + wave * 512]);
    gload16(pB0 + hK, &Bs[0][1][wave * 512]);
    gload16(pB1 + hK, &Bs[0][1][4096 + wave * 512]);
    gload16(pA0 + 64,      &As[1][0][wave * 512]);
    gload16(pA1 + 64,      &As[1][0][4096 + wave * 512]);
    gload16(pA0 + hK + 64, &As[1][1][wave * 512]);
    gload16(pA1 + hK + 64, &As[1][1][4096 + wave * 512]);
    gload16(pB0 + 64,      &Bs[1][0][wave * 512]);
    gload16(pB1 + 64,      &Bs[1][0][4096 + wave * 512]);
    gload16(pB0 + hK + 64, &Bs[1][1][wave * 512]);
    gload16(pB1 + hK + 64, &Bs[1][1][4096 + wave * 512]);
    VMCNT(8);      // tile 0 landed; tile 1 stays in flight
    BARRIER();

    for (int kt = 0; kt < NT; kt += 2) {
        const bool pf0 = (kt + 2) < NT;
        const bool pf1 = (kt + 3) < NT;
        ktile_body<0>(As, Bs, pA0, pA1, pB0, pB1, hK, 128, pf0,
                      wm, wn, r16, kg, wave, acc);
        ktile_body<1>(As, Bs, pA0, pA1, pB0, pB1, hK, 192, pf1,
                      wm, wn, r16, kg, wave, acc);
        pA0 += 128; pA1 += 128; pB0 += 128; pB1 += 128;
    }

    #pragma unroll
    for (int mi = 0; mi < 8; ++mi)
        #pragma unroll
        for (int ni = 0; ni < 4; ++ni) {
            const int row = m0 + wm * 128 + mi * 16 + kg * 4;
            const int col = n0 + wn * 64 + ni * 16 + r16;
            f32x4 v = acc[mi][ni];
            #pragma unroll
            for (int rr = 0; rr < 4; ++rr)
                Cf[(size_t)(row + rr) * ldC + col] = v[rr];
        }
}

extern "C" void kernel_launch(void* const* d_in, const int* in_sizes, int n_in,
                              void* d_out, int out_size, void* d_ws, size_t ws_size,
                              hipStream_t stream) {
    const float* x  = (const float*)d_in[0];
    const float* wg = (const float*)d_in[1];
    const float* wu = (const float*)d_in[2];
    const float* wd = (const float*)d_in[3];
    float* out = (float*)d_out;

    unsigned short* inter = (unsigned short*)d_ws;
    unsigned short* xb  = (unsigned short*)((char*)d_ws + (size_t)Md * Id * 2);
    unsigned short* wgb = xb  + (size_t)Md * Hd;
    unsigned short* wub = wgb + (size_t)Id * Hd;
    unsigned short* wdb = wub + (size_t)Id * Hd;

    k_cvt4<<<dim3(2048), dim3(256), 0, stream>>>(
        x,  xb,  Md * Hd / 8,
        wg, wgb, Id * Hd / 8,
        wu, wub, Id * Hd / 8,
        wd, wdb, Id * Hd / 8);

    k_upgate<<<dim3((Md / 256) * (Id / 128)), dim3(512), 0, stream>>>(xb, wgb, wub, inter);
    k_down<<<dim3((Md / 256) * (Hd / 256)), dim3(512), 0, stream>>>(inter, wdb, out, Id, Hd);
}

// Round 14
// 2012.638 us; speedup vs baseline: 1.9412x; 1.9412x over previous
//
#include <hip/hip_runtime.h>
#include <hip/hip_bf16.h>
#include <stdint.h>

// B,S,H,I = 4,2048,4096,11008 ; M = B*S = 8192
static constexpr int Hd = 4096;
static constexpr int Id = 11008;
static constexpr int Md = 8192;

using short8 = __attribute__((ext_vector_type(8))) short;
using f32x4  = __attribute__((ext_vector_type(4))) float;

__device__ __forceinline__ unsigned short f2bf(float x) {
    union { float f; unsigned u; } v; v.f = x;
    unsigned r = v.u + 0x7FFF + ((v.u >> 16) & 1);   // RNE
    return (unsigned short)(r >> 16);
}

typedef const __attribute__((address_space(1))) unsigned int* as1_u32p;
typedef __attribute__((address_space(3))) unsigned int* as3_u32p;

__device__ __forceinline__ void gload16(const unsigned short* g, unsigned short* l) {
    __builtin_amdgcn_global_load_lds((as1_u32p)(const void*)g, (as3_u32p)(void*)l, 16, 0, 0);
}

// swizzled chunk offset (ushort index) within a [rows][64 cols] bf16 tile.
#define AOFF(r, c) ((((r) * 8) + ((c) ^ ((r) & 7))) * 8)

#define LGKM0() do { asm volatile("s_waitcnt lgkmcnt(0)" ::: "memory"); \
                     __builtin_amdgcn_sched_barrier(0); } while (0)
#define VMCNT(n) do { asm volatile("s_waitcnt vmcnt(" #n ")" ::: "memory"); \
                      __builtin_amdgcn_sched_barrier(0); } while (0)
#define BARRIER() do { asm volatile("" ::: "memory"); __builtin_amdgcn_s_barrier(); \
                       asm volatile("" ::: "memory"); } while (0)

// ---------------------------------------------------------------------------
// fp32 -> bf16 bulk converter: all 4 tensors in one launch
// ---------------------------------------------------------------------------
__global__ __launch_bounds__(256) void k_cvt4(
    const float* __restrict__ s0, unsigned short* __restrict__ d0, int n0,
    const float* __restrict__ s1, unsigned short* __restrict__ d1, int n1,
    const float* __restrict__ s2, unsigned short* __restrict__ d2, int n2,
    const float* __restrict__ s3, unsigned short* __restrict__ d3, int n3)
{
    const int total = n0 + n1 + n2 + n3;
    int i = blockIdx.x * blockDim.x + threadIdx.x;
    const int stride = gridDim.x * blockDim.x;
    for (; i < total; i += stride) {
        const float* s; unsigned short* d; int j = i;
        if (j < n0) { s = s0; d = d0; }
        else { j -= n0;
            if (j < n1) { s = s1; d = d1; }
            else { j -= n1;
                if (j < n2) { s = s2; d = d2; }
                else { j -= n2; s = s3; d = d3; }
            }
        }
        f32x4 a = *(const f32x4*)(s + (size_t)j * 8);
        f32x4 b = *(const f32x4*)(s + (size_t)j * 8 + 4);
        short8 v;
        v[0] = (short)f2bf(a[0]); v[1] = (short)f2bf(a[1]);
        v[2] = (short)f2bf(a[2]); v[3] = (short)f2bf(a[3]);
        v[4] = (short)f2bf(b[0]); v[5] = (short)f2bf(b[1]);
        v[6] = (short)f2bf(b[2]); v[7] = (short)f2bf(b[3]);
        *reinterpret_cast<short8*>(d + (size_t)j * 8) = v;
    }
}

// ===========================================================================
// FUSED up+gate kernel. = proven R12 with the redundant pre-MFMA barrier
// removed from P1/P2/P3 (4 barriers/K-tile instead of 7).
// Safety invariant (re-derived): wave V's ds_reads complete at V's own
// lgkmcnt(0), which precedes V's arrival at the PHASE-END barrier; any wave
// staging into that buffer does so after that barrier -> all reads landed.
// vmcnt ledger identical to R12 (VMCNT(8) before the kept P4-end barrier).
// Register pressure identical to R12 (no read-ahead arrays).
// ===========================================================================
template<int D>
__device__ __forceinline__ void ug_body(
    unsigned short (&As)[2][2][8192], unsigned short (&Gs)[2][8192], unsigned short (&Us)[2][8192],
    const unsigned short* pA0, const unsigned short* pA1,
    const unsigned short* pG0, const unsigned short* pG1,
    const unsigned short* pU0, const unsigned short* pU1,
    int stoff, bool pf,
    int wm, int wn, int r16, int kg, int wave,
    f32x4 (&accg)[8][2], f32x4 (&accu)[8][2])
{
    constexpr size_t hK = (size_t)128 * Hd;
    short8 af[4][2], gf[2][2], uf[2][2];

    // ---- P1: read af-lo + gf; MFMA G mi0-3 ----
    #pragma unroll
    for (int mi = 0; mi < 4; ++mi)
        #pragma unroll
        for (int kk = 0; kk < 2; ++kk)
            af[mi][kk] = *(const short8*)&As[D][wm][AOFF(mi * 16 + r16, kk * 4 + kg)];
    #pragma unroll
    for (int ni = 0; ni < 2; ++ni)
        #pragma unroll
        for (int kk = 0; kk < 2; ++kk)
            gf[ni][kk] = *(const short8*)&Gs[D][AOFF(wn * 32 + ni * 16 + r16, kk * 4 + kg)];
    LGKM0();
    __builtin_amdgcn_s_setprio(1);
    #pragma unroll
    for (int mi = 0; mi < 4; ++mi)
        #pragma unroll
        for (int ni = 0; ni < 2; ++ni)
            #pragma unroll
            for (int kk = 0; kk < 2; ++kk)
                accg[mi][ni] = __builtin_amdgcn_mfma_f32_16x16x32_bf16(af[mi][kk], gf[ni][kk], accg[mi][ni], 0, 0, 0);
    __builtin_amdgcn_s_setprio(0);
    BARRIER();

    // ---- P2: stage G(t+2) (Gs[D] fully read in P1); read uf; MFMA U mi0-3 ----
    if (pf) {
        gload16(pG0 + stoff, &Gs[D][wave * 512]);
        gload16(pG1 + stoff, &Gs[D][4096 + wave * 512]);
    }
    #pragma unroll
    for (int ni = 0; ni < 2; ++ni)
        #pragma unroll
        for (int kk = 0; kk < 2; ++kk)
            uf[ni][kk] = *(const short8*)&Us[D][AOFF(wn * 32 + ni * 16 + r16, kk * 4 + kg)];
    LGKM0();
    __builtin_amdgcn_s_setprio(1);
    #pragma unroll
    for (int mi = 0; mi < 4; ++mi)
        #pragma unroll
        for (int ni = 0; ni < 2; ++ni)
            #pragma unroll
            for (int kk = 0; kk < 2; ++kk)
                accu[mi][ni] = __builtin_amdgcn_mfma_f32_16x16x32_bf16(af[mi][kk], uf[ni][kk], accu[mi][ni], 0, 0, 0);
    __builtin_amdgcn_s_setprio(0);
    BARRIER();

    // ---- P3: stage U(t+2) (Us[D] fully read in P2); read af-hi; MFMA G mi4-7 ----
    if (pf) {
        gload16(pU0 + stoff, &Us[D][wave * 512]);
        gload16(pU1 + stoff, &Us[D][4096 + wave * 512]);
    }
    #pragma unroll
    for (int mi = 0; mi < 4; ++mi)
        #pragma unroll
        for (int kk = 0; kk < 2; ++kk)
            af[mi][kk] = *(const short8*)&As[D][wm][AOFF((mi + 4) * 16 + r16, kk * 4 + kg)];
    LGKM0();
    __builtin_amdgcn_s_setprio(1);
    #pragma unroll
    for (int mi = 0; mi < 4; ++mi)
        #pragma unroll
        for (int ni = 0; ni < 2; ++ni)
            #pragma unroll
            for (int kk = 0; kk < 2; ++kk)
                accg[mi + 4][ni] = __builtin_amdgcn_mfma_f32_16x16x32_bf16(af[mi][kk], gf[ni][kk], accg[mi + 4][ni], 0, 0, 0);
    __builtin_amdgcn_s_setprio(0);
    BARRIER();

    // ---- P4: stage A(t+2) (As[D] last read in P3); MFMA U mi4-7 ----
    if (pf) {
        gload16(pA0 + stoff,      &As[D][0][wave * 512]);
        gload16(pA1 + stoff,      &As[D][0][4096 + wave * 512]);
        gload16(pA0 + hK + stoff, &As[D][1][wave * 512]);
        gload16(pA1 + hK + stoff, &As[D][1][4096 + wave * 512]);
    }
    __builtin_amdgcn_s_setprio(1);
    #pragma unroll
    for (int mi = 0; mi < 4; ++mi)
        #pragma unroll
        for (int ni = 0; ni < 2; ++ni)
            #pragma unroll
            for (int kk = 0; kk < 2; ++kk)
                accu[mi + 4][ni] = __builtin_amdgcn_mfma_f32_16x16x32_bf16(af[mi][kk], uf[ni][kk], accu[mi + 4][ni], 0, 0, 0);
    __builtin_amdgcn_s_setprio(0);
    if (pf) { VMCNT(8); }
    else    { VMCNT(0); }
    BARRIER();
}

__global__ __launch_bounds__(512, 2) void k_upgate(
    const unsigned short* __restrict__ A,
    const unsigned short* __restrict__ G,
    const unsigned short* __restrict__ U,
    unsigned short* __restrict__ inter)
{
    __shared__ unsigned short As[2][2][8192];
    __shared__ unsigned short Gs[2][8192];
    __shared__ unsigned short Us[2][8192];

    const int tid  = threadIdx.x;
    const int wave = tid >> 6;
    const int lane = tid & 63;
    const int wm   = wave >> 2;
    const int wn   = wave & 3;
    const int r16  = lane & 15;
    const int kg   = lane >> 4;

    const int nwg = gridDim.x;           // 2752
    const int bid = blockIdx.x;
    const int swz = (bid & 7) * (nwg >> 3) + (bid >> 3);
    const int grp = swz / 688;
    const int rem = swz % 688;
    const int m0  = (grp * 8 + (rem & 7)) * 256;
    const int n0  = (rem >> 3) * 128;

    const int i0 = tid,       r0 = i0 >> 3;
    const int i1 = 512 + tid, r1 = i1 >> 3;
    const int cc0 = (i0 & 7) ^ (r0 & 7);
    const int cc1 = (i1 & 7) ^ (r1 & 7);
    constexpr size_t hK = (size_t)128 * Hd;

    const unsigned short* pA0 = A + (size_t)(m0 + r0) * Hd + cc0 * 8;
    const unsigned short* pA1 = A + (size_t)(m0 + r1) * Hd + cc1 * 8;
    const unsigned short* pG0 = G + (size_t)(n0 + r0) * Hd + cc0 * 8;
    const unsigned short* pG1 = G + (size_t)(n0 + r1) * Hd + cc1 * 8;
    const unsigned short* pU0 = U + (size_t)(n0 + r0) * Hd + cc0 * 8;
    const unsigned short* pU1 = U + (size_t)(n0 + r1) * Hd + cc1 * 8;

    f32x4 accg[8][2] = {};
    f32x4 accu[8][2] = {};

    constexpr int NT = Hd >> 6;   // 64

    // prologue: tile 0 (A,G,U) + tile 1 (A,G,U) = 16 loads
    gload16(pA0,      &As[0][0][wave * 512]);
    gload16(pA1,      &As[0][0][4096 + wave * 512]);
    gload16(pA0 + hK, &As[0][1][wave * 512]);
    gload16(pA1 + hK, &As[0][1][4096 + wave * 512]);
    gload16(pG0,      &Gs[0][wave * 512]);
    gload16(pG1,      &Gs[0][4096 + wave * 512]);
    gload16(pU0,      &Us[0][wave * 512]);
    gload16(pU1,      &Us[0][4096 + wave * 512]);
    gload16(pA0 + 64,      &As[1][0][wave * 512]);
    gload16(pA1 + 64,      &As[1][0][4096 + wave * 512]);
    gload16(pA0 + hK + 64, &As[1][1][wave * 512]);
    gload16(pA1 + hK + 64, &As[1][1][4096 + wave * 512]);
    gload16(pG0 + 64, &Gs[1][wave * 512]);
    gload16(pG1 + 64, &Gs[1][4096 + wave * 512]);
    gload16(pU0 + 64, &Us[1][wave * 512]);
    gload16(pU1 + 64, &Us[1][4096 + wave * 512]);
    VMCNT(8);      // tile 0 landed; tile 1 in flight
    BARRIER();

    for (int kt = 0; kt < NT; kt += 2) {
        const bool pf0 = (kt + 2) < NT;
        const bool pf1 = (kt + 3) < NT;
        ug_body<0>(As, Gs, Us, pA0, pA1, pG0, pG1, pU0, pU1,
                   128, pf0, wm, wn, r16, kg, wave, accg, accu);
        ug_body<1>(As, Gs, Us, pA0, pA1, pG0, pG1, pU0, pU1,
                   192, pf1, wm, wn, r16, kg, wave, accg, accu);
        pA0 += 128; pA1 += 128; pG0 += 128; pG1 += 128; pU0 += 128; pU1 += 128;
    }

    #pragma unroll
    for (int mi = 0; mi < 8; ++mi)
        #pragma unroll
        for (int ni = 0; ni < 2; ++ni) {
            const int row = m0 + wm * 128 + mi * 16 + kg * 4;
            const int col = n0 + wn * 32 + ni * 16 + r16;
            f32x4 g = accg[mi][ni], u = accu[mi][ni];
            #pragma unroll
            for (int rr = 0; rr < 4; ++rr) {
                float gv = g[rr];
                float s  = gv / (1.0f + __expf(-gv));
                inter[(size_t)(row + rr) * Id + col] = f2bf(s * u[rr]);
            }
        }
}

// ===========================================================================
// Down GEMM. = proven R12 with pre-MFMA barriers removed (same derivation).
// Bs[D] read P1+P2 -> B(t+2)@P3; As[D] read P1+P3 -> A(t+2)@P4. VMCNT(8).
// ===========================================================================
template<int D>
__device__ __forceinline__ void ktile_body(
    unsigned short (&As)[2][2][8192], unsigned short (&Bs)[2][2][8192],
    const unsigned short* pA0, const unsigned short* pA1,
    const unsigned short* pB0, const unsigned short* pB1,
    size_t hK, int stoff, bool pf,
    int wm, int wn, int r16, int kg, int wave,
    f32x4 (&acc)[8][4])
{
    short8 af[4][2], b0f[2][2], b1f[2][2];

    // ---- P1: read af-lo + b0f; MFMA ----
    #pragma unroll
    for (int mi = 0; mi < 4; ++mi)
        #pragma unroll
        for (int kk = 0; kk < 2; ++kk)
            af[mi][kk] = *(const short8*)&As[D][wm][AOFF(mi * 16 + r16, kk * 4 + kg)];
    #pragma unroll
    for (int ni = 0; ni < 2; ++ni)
        #pragma unroll
        for (int kk = 0; kk < 2; ++kk)
            b0f[ni][kk] = *(const short8*)&Bs[D][wn >> 1][AOFF((wn & 1) * 64 + ni * 16 + r16, kk * 4 + kg)];
    LGKM0();
    __builtin_amdgcn_s_setprio(1);
    #pragma unroll
    for (int mi = 0; mi < 4; ++mi)
        #pragma unroll
        for (int ni = 0; ni < 2; ++ni)
            #pragma unroll
            for (int kk = 0; kk < 2; ++kk)
                acc[mi][ni] = __builtin_amdgcn_mfma_f32_16x16x32_bf16(af[mi][kk], b0f[ni][kk], acc[mi][ni], 0, 0, 0);
    __builtin_amdgcn_s_setprio(0);
    BARRIER();

    // ---- P2: read b1f; MFMA ----
    #pragma unroll
    for (int ni = 0; ni < 2; ++ni)
        #pragma unroll
        for (int kk = 0; kk < 2; ++kk)
            b1f[ni][kk] = *(const short8*)&Bs[D][wn >> 1][AOFF((wn & 1) * 64 + (ni + 2) * 16 + r16, kk * 4 + kg)];
    LGKM0();
    __builtin_amdgcn_s_setprio(1);
    #pragma unroll
    for (int mi = 0; mi < 4; ++mi)
        #pragma unroll
        for (int ni = 0; ni < 2; ++ni)
            #pragma unroll
            for (int kk = 0; kk < 2; ++kk)
                acc[mi][ni + 2] = __builtin_amdgcn_mfma_f32_16x16x32_bf16(af[mi][kk], b1f[ni][kk], acc[mi][ni + 2], 0, 0, 0);
    __builtin_amdgcn_s_setprio(0);
    BARRIER();

    // ---- P3: stage B(t+2) (Bs[D] fully read at P2); read af-hi; MFMA ----
    if (pf) {
        gload16(pB0 + stoff,      &Bs[D][0][wave * 512]);
        gload16(pB1 + stoff,      &Bs[D][0][4096 + wave * 512]);
        gload16(pB0 + hK + stoff, &Bs[D][1][wave * 512]);
        gload16(pB1 + hK + stoff, &Bs[D][1][4096 + wave * 512]);
    }
    #pragma unroll
    for (int mi = 0; mi < 4; ++mi)
        #pragma unroll
        for (int kk = 0; kk < 2; ++kk)
            af[mi][kk] = *(const short8*)&As[D][wm][AOFF((mi + 4) * 16 + r16, kk * 4 + kg)];
    LGKM0();
    __builtin_amdgcn_s_setprio(1);
    #pragma unroll
    for (int mi = 0; mi < 4; ++mi)
        #pragma unroll
        for (int ni = 0; ni < 2; ++ni)
            #pragma unroll
            for (int kk = 0; kk < 2; ++kk)
                acc[mi + 4][ni + 2] = __builtin_amdgcn_mfma_f32_16x16x32_bf16(af[mi][kk], b1f[ni][kk], acc[mi + 4][ni + 2], 0, 0, 0);
    __builtin_amdgcn_s_setprio(0);
    BARRIER();

    // ---- P4: stage A(t+2) (As[D] last read in P3); MFMA from regs ----
    if (pf) {
        gload16(pA0 + stoff,      &As[D][0][wave * 512]);
        gload16(pA1 + stoff,      &As[D][0][4096 + wave * 512]);
        gload16(pA0 + hK + stoff, &As[D][1][wave * 512]);
        gload16(pA1 + hK + stoff, &As[D][1][4096 + wave * 512]);
    }
    __builtin_amdgcn_s_setprio(1);
    #pragma unroll
    for (int mi = 0; mi < 4; ++mi)
        #pragma unroll
        for (int ni = 0; ni < 2; ++ni)
            #pragma unroll
            for (int kk = 0; kk < 2; ++kk)
                acc[mi + 4][ni] = __builtin_amdgcn_mfma_f32_16x16x32_bf16(af[mi][kk], b0f[ni][kk], acc[mi + 4][ni], 0, 0, 0);
    __builtin_amdgcn_s_setprio(0);
    if (pf) { VMCNT(8); }
    else    { VMCNT(0); }
    BARRIER();
}

__global__ __launch_bounds__(512, 2) void k_down(
    const unsigned short* __restrict__ A, const unsigned short* __restrict__ B,
    float* __restrict__ Cf, const int K, const int ldC)
{
    __shared__ unsigned short As[2][2][8192];
    __shared__ unsigned short Bs[2][2][8192];

    const int tid  = threadIdx.x;
    const int wave = tid >> 6;
    const int lane = tid & 63;
    const int wm   = wave >> 2;
    const int wn   = wave & 3;
    const int r16  = lane & 15;
    const int kg   = lane >> 4;

    const int nwg = gridDim.x;           // 512
    const int bid = blockIdx.x;
    const int swz = (bid & 7) * (nwg >> 3) + (bid >> 3);
    const int grp = swz / 128;
    const int rem = swz % 128;
    const int m0  = (grp * 8 + (rem & 7)) * 256;
    const int n0  = (rem >> 3) * 256;

    const int i0 = tid,       r0 = i0 >> 3;
    const int i1 = 512 + tid, r1 = i1 >> 3;
    const int cc0 = (i0 & 7) ^ (r0 & 7);
    const int cc1 = (i1 & 7) ^ (r1 & 7);
    const size_t hK = (size_t)128 * K;

    const unsigned short* pA0 = A + (size_t)(m0 + r0) * K + cc0 * 8;
    const unsigned short* pA1 = A + (size_t)(m0 + r1) * K + cc1 * 8;
    const unsigned short* pB0 = B + (size_t)(n0 + r0) * K + cc0 * 8;
    const unsigned short* pB1 = B + (size_t)(n0 + r1) * K + cc1 * 8;

    f32x4 acc[8][4] = {};

    const int NT = K >> 6;   // 172

    gload16(pA0,      &As[0][0][wave * 512]);
    gload16(pA1,      &As[0][0][4096 + wave * 512]);
    gload16(pA0 + hK, &As[0][1][wave * 512]);
    gload16(pA1 + hK, &As[0][1][4096 + wave * 512]);
    gload16(pB0,      &Bs[0][0][wave * 512]);
    gload16(pB1,      &Bs[0][0][4096 + wave * 512]);
    gload16(pB0 + hK, &Bs[0][1][wave * 512]);
    gload16(pB1 + hK, &Bs[0][1][4096 + wave * 512]);
    gload16(pA0 + 64,      &As[1][0][wave * 512]);
    gload16(pA1 + 64,      &As[1][0][4096 + wave * 512]);
    gload16(pA0 + hK + 64, &As[1][1][wave * 512]);
    gload16(pA1 + hK + 64, &As[1][1][4096 + wave * 512]);
    gload16(pB0 + 64,      &Bs[1][0][wave * 512]);
    gload16(pB1 + 64,      &Bs[1][0][4096 + wave * 512]);
    gload16(pB0 + hK + 64, &Bs[1][1][wave * 512]);
    gload16(pB1 + hK + 64, &Bs[1][1][4096 + wave * 512]);
    VMCNT(8);      // tile 0 landed; tile 1 stays in flight
    BARRIER();

    for (int kt = 0; kt < NT; kt += 2) {
        const bool pf0 = (kt + 2) < NT;
        const bool pf1 = (kt + 3) < NT;
        ktile_body<0>(As, Bs, pA0, pA1, pB0, pB1, hK, 128, pf0,
                      wm, wn, r16, kg, wave, acc);
        ktile_body<1>(As, Bs, pA0, pA1, pB0, pB1, hK, 192, pf1,
                      wm, wn, r16, kg, wave, acc);
        pA0 += 128; pA1 += 128; pB0 += 128; pB1 += 128;
    }

    #pragma unroll
    for (int mi = 0; mi < 8; ++mi)
        #pragma unroll
        for (int ni = 0; ni < 4; ++ni) {
            const int row = m0 + wm * 128 + mi * 16 + kg * 4;
            const int col = n0 + wn * 64 + ni * 16 + r16;
            f32x4 v = acc[mi][ni];
            #pragma unroll
            for (int rr = 0; rr < 4; ++rr)
                Cf[(size_t)(row + rr) * ldC + col] = v[rr];
        }
}

extern "C" void kernel_launch(void* const* d_in, const int* in_sizes, int n_in,
                              void* d_out, int out_size, void* d_ws, size_t ws_size,
                              hipStream_t stream) {
    const float* x  = (const float*)d_in[0];
    const float* wg = (const float*)d_in[1];
    const float* wu = (const float*)d_in[2];
    const float* wd = (const float*)d_in[3];
    float* out = (float*)d_out;

    unsigned short* inter = (unsigned short*)d_ws;
    unsigned short* xb  = (unsigned short*)((char*)d_ws + (size_t)Md * Id * 2);
    unsigned short* wgb = xb  + (size_t)Md * Hd;
    unsigned short* wub = wgb + (size_t)Id * Hd;
    unsigned short* wdb = wub + (size_t)Id * Hd;

    k_cvt4<<<dim3(2048), dim3(256), 0, stream>>>(
        x,  xb,  Md * Hd / 8,
        wg, wgb, Id * Hd / 8,
        wu, wub, Id * Hd / 8,
        wd, wdb, Id * Hd / 8);

    k_upgate<<<dim3((Md / 256) * (Id / 128)), dim3(512), 0, stream>>>(xb, wgb, wub, inter);
    k_down<<<dim3((Md / 256) * (Hd / 256)), dim3(512), 0, stream>>>(inter, wdb, out, Id, Hd);
}

// Round 15
// 1993.632 us; speedup vs baseline: 1.9597x; 1.0095x over previous
//
#include <hip/hip_runtime.h>
#include <hip/hip_bf16.h>
#include <stdint.h>

// B,S,H,I = 4,2048,4096,11008 ; M = B*S = 8192
static constexpr int Hd = 4096;
static constexpr int Id = 11008;
static constexpr int Md = 8192;

using short8 = __attribute__((ext_vector_type(8))) short;
using f32x4  = __attribute__((ext_vector_type(4))) float;

__device__ __forceinline__ unsigned short f2bf(float x) {
    union { float f; unsigned u; } v; v.f = x;
    unsigned r = v.u + 0x7FFF + ((v.u >> 16) & 1);   // RNE
    return (unsigned short)(r >> 16);
}

typedef const __attribute__((address_space(1))) unsigned int* as1_u32p;
typedef __attribute__((address_space(3))) unsigned int* as3_u32p;

__device__ __forceinline__ void gload16(const unsigned short* g, unsigned short* l) {
    __builtin_amdgcn_global_load_lds((as1_u32p)(const void*)g, (as3_u32p)(void*)l, 16, 0, 0);
}

// swizzled chunk offset (ushort index) within a [rows][64 cols] bf16 tile.
#define AOFF(r, c) ((((r) * 8) + ((c) ^ ((r) & 7))) * 8)

#define VMCNT(n) do { asm volatile("s_waitcnt vmcnt(" #n ")" ::: "memory"); \
                      __builtin_amdgcn_sched_barrier(0); } while (0)
#define BARRIER() do { asm volatile("" ::: "memory"); __builtin_amdgcn_s_barrier(); \
                       asm volatile("" ::: "memory"); } while (0)

// ---------------------------------------------------------------------------
// fp32 -> bf16 bulk converter: all 4 tensors in one launch
// ---------------------------------------------------------------------------
__global__ __launch_bounds__(256) void k_cvt4(
    const float* __restrict__ s0, unsigned short* __restrict__ d0, int n0,
    const float* __restrict__ s1, unsigned short* __restrict__ d1, int n1,
    const float* __restrict__ s2, unsigned short* __restrict__ d2, int n2,
    const float* __restrict__ s3, unsigned short* __restrict__ d3, int n3)
{
    const int total = n0 + n1 + n2 + n3;
    int i = blockIdx.x * blockDim.x + threadIdx.x;
    const int stride = gridDim.x * blockDim.x;
    for (; i < total; i += stride) {
        const float* s; unsigned short* d; int j = i;
        if (j < n0) { s = s0; d = d0; }
        else { j -= n0;
            if (j < n1) { s = s1; d = d1; }
            else { j -= n1;
                if (j < n2) { s = s2; d = d2; }
                else { j -= n2; s = s3; d = d3; }
            }
        }
        f32x4 a = *(const f32x4*)(s + (size_t)j * 8);
        f32x4 b = *(const f32x4*)(s + (size_t)j * 8 + 4);
        short8 v;
        v[0] = (short)f2bf(a[0]); v[1] = (short)f2bf(a[1]);
        v[2] = (short)f2bf(a[2]); v[3] = (short)f2bf(a[3]);
        v[4] = (short)f2bf(b[0]); v[5] = (short)f2bf(b[1]);
        v[6] = (short)f2bf(b[2]); v[7] = (short)f2bf(b[3]);
        *reinterpret_cast<short8*>(d + (size_t)j * 8) = v;
    }
}

// ===========================================================================
// FUSED up+gate kernel. = proven R14 with the explicit per-phase lgkm-drain
// removed: fragment loads are compiler-visible, so hipcc inserts fine-grained
// per-use lgkmcnt(N) — MFMAs start as soon as their own operands land, and
// read issue overlaps the MFMA cluster within a wave.
// Cross-wave safety unchanged: all fragment uses precede the phase-end
// BARRIER (asm "memory" pins ds_reads before it; compiler waits guarantee
// completion before use), so the R14 staging invariant holds verbatim.
// vmcnt ledger (gload_lds) identical to R14.
// ===========================================================================
template<int D>
__device__ __forceinline__ void ug_body(
    unsigned short (&As)[2][2][8192], unsigned short (&Gs)[2][8192], unsigned short (&Us)[2][8192],
    const unsigned short* pA0, const unsigned short* pA1,
    const unsigned short* pG0, const unsigned short* pG1,
    const unsigned short* pU0, const unsigned short* pU1,
    int stoff, bool pf,
    int wm, int wn, int r16, int kg, int wave,
    f32x4 (&accg)[8][2], f32x4 (&accu)[8][2])
{
    constexpr size_t hK = (size_t)128 * Hd;
    short8 af[4][2], gf[2][2], uf[2][2];

    // ---- P1: read af-lo + gf; MFMA G mi0-3 ----
    #pragma unroll
    for (int mi = 0; mi < 4; ++mi)
        #pragma unroll
        for (int kk = 0; kk < 2; ++kk)
            af[mi][kk] = *(const short8*)&As[D][wm][AOFF(mi * 16 + r16, kk * 4 + kg)];
    #pragma unroll
    for (int ni = 0; ni < 2; ++ni)
        #pragma unroll
        for (int kk = 0; kk < 2; ++kk)
            gf[ni][kk] = *(const short8*)&Gs[D][AOFF(wn * 32 + ni * 16 + r16, kk * 4 + kg)];
    __builtin_amdgcn_s_setprio(1);
    #pragma unroll
    for (int mi = 0; mi < 4; ++mi)
        #pragma unroll
        for (int ni = 0; ni < 2; ++ni)
            #pragma unroll
            for (int kk = 0; kk < 2; ++kk)
                accg[mi][ni] = __builtin_amdgcn_mfma_f32_16x16x32_bf16(af[mi][kk], gf[ni][kk], accg[mi][ni], 0, 0, 0);
    __builtin_amdgcn_s_setprio(0);
    BARRIER();

    // ---- P2: stage G(t+2) (Gs[D] fully read in P1); read uf; MFMA U mi0-3 ----
    if (pf) {
        gload16(pG0 + stoff, &Gs[D][wave * 512]);
        gload16(pG1 + stoff, &Gs[D][4096 + wave * 512]);
    }
    #pragma unroll
    for (int ni = 0; ni < 2; ++ni)
        #pragma unroll
        for (int kk = 0; kk < 2; ++kk)
            uf[ni][kk] = *(const short8*)&Us[D][AOFF(wn * 32 + ni * 16 + r16, kk * 4 + kg)];
    __builtin_amdgcn_s_setprio(1);
    #pragma unroll
    for (int mi = 0; mi < 4; ++mi)
        #pragma unroll
        for (int ni = 0; ni < 2; ++ni)
            #pragma unroll
            for (int kk = 0; kk < 2; ++kk)
                accu[mi][ni] = __builtin_amdgcn_mfma_f32_16x16x32_bf16(af[mi][kk], uf[ni][kk], accu[mi][ni], 0, 0, 0);
    __builtin_amdgcn_s_setprio(0);
    BARRIER();

    // ---- P3: stage U(t+2) (Us[D] fully read in P2); read af-hi; MFMA G mi4-7 ----
    if (pf) {
        gload16(pU0 + stoff, &Us[D][wave * 512]);
        gload16(pU1 + stoff, &Us[D][4096 + wave * 512]);
    }
    #pragma unroll
    for (int mi = 0; mi < 4; ++mi)
        #pragma unroll
        for (int kk = 0; kk < 2; ++kk)
            af[mi][kk] = *(const short8*)&As[D][wm][AOFF((mi + 4) * 16 + r16, kk * 4 + kg)];
    __builtin_amdgcn_s_setprio(1);
    #pragma unroll
    for (int mi = 0; mi < 4; ++mi)
        #pragma unroll
        for (int ni = 0; ni < 2; ++ni)
            #pragma unroll
            for (int kk = 0; kk < 2; ++kk)
                accg[mi + 4][ni] = __builtin_amdgcn_mfma_f32_16x16x32_bf16(af[mi][kk], gf[ni][kk], accg[mi + 4][ni], 0, 0, 0);
    __builtin_amdgcn_s_setprio(0);
    BARRIER();

    // ---- P4: stage A(t+2) (As[D] last read in P3); MFMA U mi4-7 ----
    if (pf) {
        gload16(pA0 + stoff,      &As[D][0][wave * 512]);
        gload16(pA1 + stoff,      &As[D][0][4096 + wave * 512]);
        gload16(pA0 + hK + stoff, &As[D][1][wave * 512]);
        gload16(pA1 + hK + stoff, &As[D][1][4096 + wave * 512]);
    }
    __builtin_amdgcn_s_setprio(1);
    #pragma unroll
    for (int mi = 0; mi < 4; ++mi)
        #pragma unroll
        for (int ni = 0; ni < 2; ++ni)
            #pragma unroll
            for (int kk = 0; kk < 2; ++kk)
                accu[mi + 4][ni] = __builtin_amdgcn_mfma_f32_16x16x32_bf16(af[mi][kk], uf[ni][kk], accu[mi + 4][ni], 0, 0, 0);
    __builtin_amdgcn_s_setprio(0);
    if (pf) { VMCNT(8); }
    else    { VMCNT(0); }
    BARRIER();
}

__global__ __launch_bounds__(512, 2) void k_upgate(
    const unsigned short* __restrict__ A,
    const unsigned short* __restrict__ G,
    const unsigned short* __restrict__ U,
    unsigned short* __restrict__ inter)
{
    __shared__ unsigned short As[2][2][8192];
    __shared__ unsigned short Gs[2][8192];
    __shared__ unsigned short Us[2][8192];

    const int tid  = threadIdx.x;
    const int wave = tid >> 6;
    const int lane = tid & 63;
    const int wm   = wave >> 2;
    const int wn   = wave & 3;
    const int r16  = lane & 15;
    const int kg   = lane >> 4;

    const int nwg = gridDim.x;           // 2752
    const int bid = blockIdx.x;
    const int swz = (bid & 7) * (nwg >> 3) + (bid >> 3);
    const int grp = swz / 688;
    const int rem = swz % 688;
    const int m0  = (grp * 8 + (rem & 7)) * 256;
    const int n0  = (rem >> 3) * 128;

    const int i0 = tid,       r0 = i0 >> 3;
    const int i1 = 512 + tid, r1 = i1 >> 3;
    const int cc0 = (i0 & 7) ^ (r0 & 7);
    const int cc1 = (i1 & 7) ^ (r1 & 7);
    constexpr size_t hK = (size_t)128 * Hd;

    const unsigned short* pA0 = A + (size_t)(m0 + r0) * Hd + cc0 * 8;
    const unsigned short* pA1 = A + (size_t)(m0 + r1) * Hd + cc1 * 8;
    const unsigned short* pG0 = G + (size_t)(n0 + r0) * Hd + cc0 * 8;
    const unsigned short* pG1 = G + (size_t)(n0 + r1) * Hd + cc1 * 8;
    const unsigned short* pU0 = U + (size_t)(n0 + r0) * Hd + cc0 * 8;
    const unsigned short* pU1 = U + (size_t)(n0 + r1) * Hd + cc1 * 8;

    f32x4 accg[8][2] = {};
    f32x4 accu[8][2] = {};

    constexpr int NT = Hd >> 6;   // 64

    // prologue: tile 0 (A,G,U) + tile 1 (A,G,U) = 16 loads
    gload16(pA0,      &As[0][0][wave * 512]);
    gload16(pA1,      &As[0][0][4096 + wave * 512]);
    gload16(pA0 + hK, &As[0][1][wave * 512]);
    gload16(pA1 + hK, &As[0][1][4096 + wave * 512]);
    gload16(pG0,      &Gs[0][wave * 512]);
    gload16(pG1,      &Gs[0][4096 + wave * 512]);
    gload16(pU0,      &Us[0][wave * 512]);
    gload16(pU1,      &Us[0][4096 + wave * 512]);
    gload16(pA0 + 64,      &As[1][0][wave * 512]);
    gload16(pA1 + 64,      &As[1][0][4096 + wave * 512]);
    gload16(pA0 + hK + 64, &As[1][1][wave * 512]);
    gload16(pA1 + hK + 64, &As[1][1][4096 + wave * 512]);
    gload16(pG0 + 64, &Gs[1][wave * 512]);
    gload16(pG1 + 64, &Gs[1][4096 + wave * 512]);
    gload16(pU0 + 64, &Us[1][wave * 512]);
    gload16(pU1 + 64, &Us[1][4096 + wave * 512]);
    VMCNT(8);      // tile 0 landed; tile 1 in flight
    BARRIER();

    for (int kt = 0; kt < NT; kt += 2) {
        const bool pf0 = (kt + 2) < NT;
        const bool pf1 = (kt + 3) < NT;
        ug_body<0>(As, Gs, Us, pA0, pA1, pG0, pG1, pU0, pU1,
                   128, pf0, wm, wn, r16, kg, wave, accg, accu);
        ug_body<1>(As, Gs, Us, pA0, pA1, pG0, pG1, pU0, pU1,
                   192, pf1, wm, wn, r16, kg, wave, accg, accu);
        pA0 += 128; pA1 += 128; pG0 += 128; pG1 += 128; pU0 += 128; pU1 += 128;
    }

    #pragma unroll
    for (int mi = 0; mi < 8; ++mi)
        #pragma unroll
        for (int ni = 0; ni < 2; ++ni) {
            const int row = m0 + wm * 128 + mi * 16 + kg * 4;
            const int col = n0 + wn * 32 + ni * 16 + r16;
            f32x4 g = accg[mi][ni], u = accu[mi][ni];
            #pragma unroll
            for (int rr = 0; rr < 4; ++rr) {
                float gv = g[rr];
                float s  = gv / (1.0f + __expf(-gv));
                inter[(size_t)(row + rr) * Id + col] = f2bf(s * u[rr]);
            }
        }
}

// ===========================================================================
// Down GEMM. = proven R14 minus explicit lgkm drains (same derivation).
// Bs[D] read P1+P2 -> B(t+2)@P3; As[D] read P1+P3 -> A(t+2)@P4. VMCNT(8).
// ===========================================================================
template<int D>
__device__ __forceinline__ void ktile_body(
    unsigned short (&As)[2][2][8192], unsigned short (&Bs)[2][2][8192],
    const unsigned short* pA0, const unsigned short* pA1,
    const unsigned short* pB0, const unsigned short* pB1,
    size_t hK, int stoff, bool pf,
    int wm, int wn, int r16, int kg, int wave,
    f32x4 (&acc)[8][4])
{
    short8 af[4][2], b0f[2][2], b1f[2][2];

    // ---- P1: read af-lo + b0f; MFMA ----
    #pragma unroll
    for (int mi = 0; mi < 4; ++mi)
        #pragma unroll
        for (int kk = 0; kk < 2; ++kk)
            af[mi][kk] = *(const short8*)&As[D][wm][AOFF(mi * 16 + r16, kk * 4 + kg)];
    #pragma unroll
    for (int ni = 0; ni < 2; ++ni)
        #pragma unroll
        for (int kk = 0; kk < 2; ++kk)
            b0f[ni][kk] = *(const short8*)&Bs[D][wn >> 1][AOFF((wn & 1) * 64 + ni * 16 + r16, kk * 4 + kg)];
    __builtin_amdgcn_s_setprio(1);
    #pragma unroll
    for (int mi = 0; mi < 4; ++mi)
        #pragma unroll
        for (int ni = 0; ni < 2; ++ni)
            #pragma unroll
            for (int kk = 0; kk < 2; ++kk)
                acc[mi][ni] = __builtin_amdgcn_mfma_f32_16x16x32_bf16(af[mi][kk], b0f[ni][kk], acc[mi][ni], 0, 0, 0);
    __builtin_amdgcn_s_setprio(0);
    BARRIER();

    // ---- P2: read b1f; MFMA ----
    #pragma unroll
    for (int ni = 0; ni < 2; ++ni)
        #pragma unroll
        for (int kk = 0; kk < 2; ++kk)
            b1f[ni][kk] = *(const short8*)&Bs[D][wn >> 1][AOFF((wn & 1) * 64 + (ni + 2) * 16 + r16, kk * 4 + kg)];
    __builtin_amdgcn_s_setprio(1);
    #pragma unroll
    for (int mi = 0; mi < 4; ++mi)
        #pragma unroll
        for (int ni = 0; ni < 2; ++ni)
            #pragma unroll
            for (int kk = 0; kk < 2; ++kk)
                acc[mi][ni + 2] = __builtin_amdgcn_mfma_f32_16x16x32_bf16(af[mi][kk], b1f[ni][kk], acc[mi][ni + 2], 0, 0, 0);
    __builtin_amdgcn_s_setprio(0);
    BARRIER();

    // ---- P3: stage B(t+2) (Bs[D] fully read at P2); read af-hi; MFMA ----
    if (pf) {
        gload16(pB0 + stoff,      &Bs[D][0][wave * 512]);
        gload16(pB1 + stoff,      &Bs[D][0][4096 + wave * 512]);
        gload16(pB0 + hK + stoff, &Bs[D][1][wave * 512]);
        gload16(pB1 + hK + stoff, &Bs[D][1][4096 + wave * 512]);
    }
    #pragma unroll
    for (int mi = 0; mi < 4; ++mi)
        #pragma unroll
        for (int kk = 0; kk < 2; ++kk)
            af[mi][kk] = *(const short8*)&As[D][wm][AOFF((mi + 4) * 16 + r16, kk * 4 + kg)];
    __builtin_amdgcn_s_setprio(1);
    #pragma unroll
    for (int mi = 0; mi < 4; ++mi)
        #pragma unroll
        for (int ni = 0; ni < 2; ++ni)
            #pragma unroll
            for (int kk = 0; kk < 2; ++kk)
                acc[mi + 4][ni + 2] = __builtin_amdgcn_mfma_f32_16x16x32_bf16(af[mi][kk], b1f[ni][kk], acc[mi + 4][ni + 2], 0, 0, 0);
    __builtin_amdgcn_s_setprio(0);
    BARRIER();

    // ---- P4: stage A(t+2) (As[D] last read in P3); MFMA from regs ----
    if (pf) {
        gload16(pA0 + stoff,      &As[D][0][wave * 512]);
        gload16(pA1 + stoff,      &As[D][0][4096 + wave * 512]);
        gload16(pA0 + hK + stoff, &As[D][1][wave * 512]);
        gload16(pA1 + hK + stoff, &As[D][1][4096 + wave * 512]);
    }
    __builtin_amdgcn_s_setprio(1);
    #pragma unroll
    for (int mi = 0; mi < 4; ++mi)
        #pragma unroll
        for (int ni = 0; ni < 2; ++ni)
            #pragma unroll
            for (int kk = 0; kk < 2; ++kk)
                acc[mi + 4][ni] = __builtin_amdgcn_mfma_f32_16x16x32_bf16(af[mi][kk], b0f[ni][kk], acc[mi + 4][ni], 0, 0, 0);
    __builtin_amdgcn_s_setprio(0);
    if (pf) { VMCNT(8); }
    else    { VMCNT(0); }
    BARRIER();
}

__global__ __launch_bounds__(512, 2) void k_down(
    const unsigned short* __restrict__ A, const unsigned short* __restrict__ B,
    float* __restrict__ Cf, const int K, const int ldC)
{
    __shared__ unsigned short As[2][2][8192];
    __shared__ unsigned short Bs[2][2][8192];

    const int tid  = threadIdx.x;
    const int wave = tid >> 6;
    const int lane = tid & 63;
    const int wm   = wave >> 2;
    const int wn   = wave & 3;
    const int r16  = lane & 15;
    const int kg   = lane >> 4;

    const int nwg = gridDim.x;           // 512
    const int bid = blockIdx.x;
    const int swz = (bid & 7) * (nwg >> 3) + (bid >> 3);
    const int grp = swz / 128;
    const int rem = swz % 128;
    const int m0  = (grp * 8 + (rem & 7)) * 256;
    const int n0  = (rem >> 3) * 256;

    const int i0 = tid,       r0 = i0 >> 3;
    const int i1 = 512 + tid, r1 = i1 >> 3;
    const int cc0 = (i0 & 7) ^ (r0 & 7);
    const int cc1 = (i1 & 7) ^ (r1 & 7);
    const size_t hK = (size_t)128 * K;

    const unsigned short* pA0 = A + (size_t)(m0 + r0) * K + cc0 * 8;
    const unsigned short* pA1 = A + (size_t)(m0 + r1) * K + cc1 * 8;
    const unsigned short* pB0 = B + (size_t)(n0 + r0) * K + cc0 * 8;
    const unsigned short* pB1 = B + (size_t)(n0 + r1) * K + cc1 * 8;

    f32x4 acc[8][4] = {};

    const int NT = K >> 6;   // 172

    gload16(pA0,      &As[0][0][wave * 512]);
    gload16(pA1,      &As[0][0][4096 + wave * 512]);
    gload16(pA0 + hK, &As[0][1][wave * 512]);
    gload16(pA1 + hK, &As[0][1][4096 + wave * 512]);
    gload16(pB0,      &Bs[0][0][wave * 512]);
    gload16(pB1,      &Bs[0][0][4096 + wave * 512]);
    gload16(pB0 + hK, &Bs[0][1][wave * 512]);
    gload16(pB1 + hK, &Bs[0][1][4096 + wave * 512]);
    gload16(pA0 + 64,      &As[1][0][wave * 512]);
    gload16(pA1 + 64,      &As[1][0][4096 + wave * 512]);
    gload16(pA0 + hK + 64, &As[1][1][wave * 512]);
    gload16(pA1 + hK + 64, &As[1][1][4096 + wave * 512]);
    gload16(pB0 + 64,      &Bs[1][0][wave * 512]);
    gload16(pB1 + 64,      &Bs[1][0][4096 + wave * 512]);
    gload16(pB0 + hK + 64, &Bs[1][1][wave * 512]);
    gload16(pB1 + hK + 64, &Bs[1][1][4096 + wave * 512]);
    VMCNT(8);      // tile 0 landed; tile 1 stays in flight
    BARRIER();

    for (int kt = 0; kt < NT; kt += 2) {
        const bool pf0 = (kt + 2) < NT;
        const bool pf1 = (kt + 3) < NT;
        ktile_body<0>(As, Bs, pA0, pA1, pB0, pB1, hK, 128, pf0,
                      wm, wn, r16, kg, wave, acc);
        ktile_body<1>(As, Bs, pA0, pA1, pB0, pB1, hK, 192, pf1,
                      wm, wn, r16, kg, wave, acc);
        pA0 += 128; pA1 += 128; pB0 += 128; pB1 += 128;
    }

    #pragma unroll
    for (int mi = 0; mi < 8; ++mi)
        #pragma unroll
        for (int ni = 0; ni < 4; ++ni) {
            const int row = m0 + wm * 128 + mi * 16 + kg * 4;
            const int col = n0 + wn * 64 + ni * 16 + r16;
            f32x4 v = acc[mi][ni];
            #pragma unroll
            for (int rr = 0; rr < 4; ++rr)
                Cf[(size_t)(row + rr) * ldC + col] = v[rr];
        }
}

extern "C" void kernel_launch(void* const* d_in, const int* in_sizes, int n_in,
                              void* d_out, int out_size, void* d_ws, size_t ws_size,
                              hipStream_t stream) {
    const float* x  = (const float*)d_in[0];
    const float* wg = (const float*)d_in[1];
    const float* wu = (const float*)d_in[2];
    const float* wd = (const float*)d_in[3];
    float* out = (float*)d_out;

    unsigned short* inter = (unsigned short*)d_ws;
    unsigned short* xb  = (unsigned short*)((char*)d_ws + (size_t)Md * Id * 2);
    unsigned short* wgb = xb  + (size_t)Md * Hd;
    unsigned short* wub = wgb + (size_t)Id * Hd;
    unsigned short* wdb = wub + (size_t)Id * Hd;

    k_cvt4<<<dim3(2048), dim3(256), 0, stream>>>(
        x,  xb,  Md * Hd / 8,
        wg, wgb, Id * Hd / 8,
        wu, wub, Id * Hd / 8,
        wd, wdb, Id * Hd / 8);

    k_upgate<<<dim3((Md / 256) * (Id / 128)), dim3(512), 0, stream>>>(xb, wgb, wub, inter);
    k_down<<<dim3((Md / 256) * (Hd / 256)), dim3(512), 0, stream>>>(inter, wdb, out, Id, Hd);
}